// Round 8
// baseline (130.681 us; speedup 1.0000x reference)
//
#include <hip/hip_runtime.h>
#include <hip/hip_bf16.h>

typedef __bf16 bf16;
typedef bf16 bf16x2 __attribute__((ext_vector_type(2)));
typedef bf16 bf16x8 __attribute__((ext_vector_type(8)));
typedef float f32x2 __attribute__((ext_vector_type(2)));
typedef float f32x4 __attribute__((ext_vector_type(4)));
typedef float f32x16 __attribute__((ext_vector_type(16)));
typedef unsigned int uint;

namespace {
constexpr int kB  = 32;    // batch
constexpr int kT  = 2048;  // seq len
constexpr int kD  = 64;    // head dim
constexpr int QB  = 128;   // q rows per block (4 waves x 32)
constexpr float THR = 8.f; // defer-rescale threshold (T13)
// split-KV workspace: per split chunk: O_part[128][64] f32 + m[128] + l[128]
constexpr int CHUNK_F = 128 * 64 + 128 + 128;     // 8448 floats = 33792 B
constexpr size_t WS_NEED = (size_t)512 * CHUNK_F * 4;  // 512 split chunks
}

// Flash-attention fwd, causal, fp32 in/out, bf16 MFMA (32x32x16, swapped QK^T).
// S^T = mfma(K,Q): lane owns q=lane&31; keys split lane<->lane^32. Softmax
// lane-local + ONE shfl_xor(32); PV B-frag via pack + v_permlane32_swap_b32
// (vdst MUST be the low-key word — round-4 bug). Split-KV: heavy q-blocks
// (j>=8) split KV range in 2 halves -> partials in d_ws, merged by fa_merge
// (round-5 post-mortem: makespan was the 32-iter heavy block; occupancy 12.5%
// = half its 25% cap). __launch_bounds__(256,2): (256,4) forced VGPR=64 ->
// 700MB scratch spill (round 2). Do not re-add.
// (Rounds 6/7 were infra failures — container death / GPU capacity; source
// unchanged, never executed.)
__global__ __launch_bounds__(256, 2)
void fa_part(const float* __restrict__ Qg, const float* __restrict__ Kg,
             const float* __restrict__ Vg, float* __restrict__ Og,
             float* __restrict__ Wg, int mode) {
  const int tid  = (int)threadIdx.x;
  const int wid  = tid >> 6;
  const int lane = tid & 63;
  const int hi   = lane >> 5;    // half of wave: which k-subblock this lane feeds
  const int ql   = lane & 31;    // this lane's q row (relative), and d row for PV

  // ---- block decode: (batch, q-block j, tile range [t0,t1), split?)
  const int bid = (int)blockIdx.x;
  const int b   = bid & 31;
  const int u   = bid >> 5;
  int j, t0, t1, sc = 0; bool split;
  if (mode) {
    // size-descending schedule: splits of j=8..15 (halves of j+1 tiles)
    // interleaved with unsplit j=0..7 (2(j+1) tiles). max chunk = 16 tiles.
    static const signed char JT[24] = {15,15,7,14,14,13,13,6,12,12,11,11,5,10,10,9,9,4,8,8,3,2,1,0};
    static const signed char HT[24] = { 0, 1,-1, 0, 1, 0, 1,-1, 0, 1, 0, 1,-1, 0, 1, 0, 1,-1, 0, 1,-1,-1,-1,-1};
    j = JT[u]; const int h = HT[u];
    if (h < 0) { split = false; t0 = 0; t1 = 2 * (j + 1); }
    else { split = true; t0 = h * (j + 1); t1 = t0 + (j + 1); sc = b * 16 + 2 * (15 - j) + h; }
  } else {
    j = 15 - u; split = false; t0 = 0; t1 = 2 * (j + 1);   // heavy-first fallback
  }
  const int q0   = j * QB;
  const int qw   = q0 + wid * 32;
  const int qrow = qw + ql;

  // lK/lV during main loop (16KB); reused as fp32 transpose buffer in epilogue.
  __shared__ __align__(16) char smem[4 * 32 * 36 * 4];  // 18432 B
  bf16* lK = (bf16*)smem;            // [64 keys][64 d], swizzled ^((row&7)<<3)
  bf16* lV = (bf16*)(smem + 8192);   // V^T [64 d][64 keys], swizzled ^((d&7)<<3)

  const float* Qb = Qg + ((size_t)b * kT + qw) * kD;
  const float* Kb = Kg + (size_t)b * kT * kD;
  const float* Vb = Vg + (size_t)b * kT * kD;
  float*       Ob = Og + ((size_t)b * kT + qw) * kD;

  // ---- Q fragments (B-operand of swapped QK): col=q=ql, k=hi*8+j, per 16-d block
  bf16x8 qf[4];
#pragma unroll
  for (int db = 0; db < 4; ++db) {
    const float* s = Qb + (size_t)ql * kD + db * 16 + hi * 8;
    f32x4 f0 = *(const f32x4*)s, f1 = *(const f32x4*)(s + 4);
    bf16x8 q;
#pragma unroll
    for (int jj = 0; jj < 4; ++jj) {
      q[jj]     = (bf16)(f0[jj] * 0.125f);   // 1/sqrt(64) folded, exact
      q[jj + 4] = (bf16)(f1[jj] * 0.125f);
    }
    qf[db] = q;
  }

  f32x16 ot0 = {}, ot1 = {};   // O^T accum: d = dt*32 + (reg&3)+8*(reg>>2)+4*hi, q=ql
  float m_s = -1e30f, l_s = 0.f;

  // staging thread->data maps (swizzles verified 0-conflict)
  const int krow = tid >> 2;          // 0..63
  const int kc16 = (tid & 3) << 4;    // 0,16,32,48
  const int vkey = (tid & 31) << 1;   // 0..62 even
  const int vd0  = (tid >> 5) << 3;   // 0..56

  f32x4 kp0, kp1, kp2, kp3, vp0, vp1, vp2, vp3;  // named: no scratch (round-2 lesson)

#define LOADK(KV)                                                      \
  {                                                                    \
    const float* s_ = Kb + (size_t)((KV) + krow) * kD + kc16;          \
    kp0 = ((const f32x4*)s_)[0]; kp1 = ((const f32x4*)s_)[1];          \
    kp2 = ((const f32x4*)s_)[2]; kp3 = ((const f32x4*)s_)[3];          \
  }
#define LOADV(KV)                                                      \
  {                                                                    \
    const float* s0_ = Vb + (size_t)((KV) + vkey) * kD + vd0;          \
    const float* s1_ = s0_ + kD;                                       \
    vp0 = ((const f32x4*)s0_)[0]; vp1 = ((const f32x4*)s0_)[1];        \
    vp2 = ((const f32x4*)s1_)[0]; vp3 = ((const f32x4*)s1_)[1];        \
  }
#define STAGEK()                                                       \
  {                                                                    \
    bf16x8 h0_, h1_;                                                   \
    _Pragma("unroll") for (int jj = 0; jj < 4; ++jj) {                 \
      h0_[jj] = (bf16)kp0[jj]; h0_[jj + 4] = (bf16)kp1[jj];            \
      h1_[jj] = (bf16)kp2[jj]; h1_[jj + 4] = (bf16)kp3[jj];            \
    }                                                                  \
    *(bf16x8*)&lK[(krow * 64 + kc16)     ^ ((krow & 7) << 3)] = h0_;   \
    *(bf16x8*)&lK[(krow * 64 + kc16 + 8) ^ ((krow & 7) << 3)] = h1_;   \
  }
#define STAGEV()                                                       \
  {                                                                    \
    _Pragma("unroll") for (int jj = 0; jj < 8; ++jj) {                 \
      int d_ = vd0 + jj;                                               \
      float a0_ = (jj < 4) ? vp0[jj] : vp1[jj - 4];                    \
      float a1_ = (jj < 4) ? vp2[jj] : vp3[jj - 4];                    \
      int e_ = (d_ * 64 + vkey) ^ ((d_ & 7) << 3);                     \
      *(bf16x2*)&lV[e_] = (bf16x2){(bf16)a0_, (bf16)a1_};              \
    }                                                                  \
  }

  const int kv0 = t0 * 64, kv1 = t1 * 64;
  LOADK(kv0) LOADV(kv0)
  for (int kv = kv0; kv < kv1; kv += 64) {
    STAGEK() STAGEV()
    __syncthreads();
    if (kv + 64 < kv1) { LOADK(kv + 64) LOADV(kv + 64) }  // issue early

    if (kv <= qw) {                       // wave-uniform causal skip
      const int nkb = (kv + 32 <= qw) ? 2 : 1;  // active 32-key subblocks

      // ---- S^T = K·Q^T : C col=q=ql, row=key_rel=(reg&3)+8*(reg>>2)+4*hi
      f32x16 st0 = {}, st1 = {};
      __builtin_amdgcn_s_setprio(1);
#pragma unroll
      for (int db = 0; db < 4; ++db) {
        bf16x8 kf = *(const bf16x8*)&lK[(ql * 64 + db * 16 + hi * 8) ^ ((ql & 7) << 3)];
        st0 = __builtin_amdgcn_mfma_f32_32x32x16_bf16(kf, qf[db], st0, 0, 0, 0);
      }
      if (nkb == 2) {
        const int r1 = 32 + ql;
#pragma unroll
        for (int db = 0; db < 4; ++db) {
          bf16x8 kf = *(const bf16x8*)&lK[(r1 * 64 + db * 16 + hi * 8) ^ ((r1 & 7) << 3)];
          st1 = __builtin_amdgcn_mfma_f32_32x32x16_bf16(kf, qf[db], st1, 0, 0, 0);
        }
      }
      __builtin_amdgcn_s_setprio(0);

      // ---- causal mask (boundary tile only)
      if (kv + (nkb << 5) > qw) {
#pragma unroll
        for (int reg = 0; reg < 16; ++reg) {
          int krel = (reg & 3) + 8 * (reg >> 2) + 4 * hi;
          if (kv + krel > qrow) st0[reg] = -1e30f;
          if (nkb == 2 && kv + 32 + krel > qrow) st1[reg] = -1e30f;
        }
      }

      // ---- online softmax: lane-local + one cross-half shfl
      float mx = -1e30f;
#pragma unroll
      for (int r = 0; r < 16; ++r) mx = fmaxf(mx, st0[r]);
      if (nkb == 2) {
#pragma unroll
        for (int r = 0; r < 16; ++r) mx = fmaxf(mx, st1[r]);
      }
      mx = fmaxf(mx, __shfl_xor(mx, 32));
      const bool defer = (__all((mx - m_s) <= THR) != 0);
      float mn = m_s;
      if (!defer) {
        mn = fmaxf(m_s, mx);
        float corr = __expf(m_s - mn);
        m_s = mn;
        l_s *= corr;
#pragma unroll
        for (int r = 0; r < 16; ++r) { ot0[r] *= corr; ot1[r] *= corr; }
      }
      float ls = 0.f;
#pragma unroll
      for (int r = 0; r < 16; ++r) { float p = __expf(st0[r] - mn); st0[r] = p; ls += p; }
      if (nkb == 2) {
#pragma unroll
        for (int r = 0; r < 16; ++r) { float p = __expf(st1[r] - mn); st1[r] = p; ls += p; }
      }
      ls += __shfl_xor(ls, 32);
      l_s += ls;

      // ---- pack P to bf16 word pairs: w[kb*8+m] = (p[2m], p[2m+1])
      uint w_[16];
#pragma unroll
      for (int m = 0; m < 8; ++m) {
        bf16x2 t = {(bf16)st0[2 * m], (bf16)st0[2 * m + 1]};
        w_[m] = __builtin_bit_cast(uint, t);
      }
      if (nkb == 2) {
#pragma unroll
        for (int m = 0; m < 8; ++m) {
          bf16x2 t = {(bf16)st1[2 * m], (bf16)st1[2 * m + 1]};
          w_[8 + m] = __builtin_bit_cast(uint, t);
        }
      }

      // ---- PV: per 16-key slice ks, B-frag via 2 permlane32_swap.
      // vdst = LOW-key word (w[mb]); after swap:
      //   w[mb]   = {lo: keys(0,1),  hi: keys(8,9)}   -> frag word0
      //   w[mb+2] = {lo: keys(4,5),  hi: keys(12,13)} -> frag word2
#pragma unroll
      for (int ks = 0; ks < 4; ++ks) {
        if (ks < 2 * nkb) {
          const int mb = (ks >> 1) * 8 + (ks & 1) * 4;
          uint a0 = w_[mb], a1 = w_[mb + 1], b0 = w_[mb + 2], b1 = w_[mb + 3];
          asm volatile("v_permlane32_swap_b32 %0, %1" : "+v"(a0), "+v"(b0));
          asm volatile("v_permlane32_swap_b32 %0, %1" : "+v"(a1), "+v"(b1));
          union { uint u4[4]; bf16x8 v; } pc;
          pc.u4[0] = a0; pc.u4[1] = a1; pc.u4[2] = b0; pc.u4[3] = b1;
          const bf16x8 pf = pc.v;
          __builtin_amdgcn_s_setprio(1);
          {
            bf16x8 vf0 = *(const bf16x8*)&lV[(ql * 64 + ks * 16 + hi * 8) ^ ((ql & 7) << 3)];
            ot0 = __builtin_amdgcn_mfma_f32_32x32x16_bf16(vf0, pf, ot0, 0, 0, 0);
            const int d1 = 32 + ql;
            bf16x8 vf1 = *(const bf16x8*)&lV[(d1 * 64 + ks * 16 + hi * 8) ^ ((d1 & 7) << 3)];
            ot1 = __builtin_amdgcn_mfma_f32_32x32x16_bf16(vf1, pf, ot1, 0, 0, 0);
          }
          __builtin_amdgcn_s_setprio(0);
        }
      }
    }
    __syncthreads();
  }

  // ---- epilogue: via per-wave LDS transpose -> coalesced stores.
  // unsplit: O = acc/l to global. split: unnormalized acc + m/l to workspace.
  const float scl = split ? 1.0f : (1.0f / l_s);
  float* outp = split ? (Wg + (size_t)sc * CHUNK_F + (size_t)(wid * 32) * kD) : Ob;
  float* ep = (float*)(void*)smem + wid * (32 * 36);  // pad 36: aligned f32x4 reads
#pragma unroll
  for (int dt = 0; dt < 2; ++dt) {
    __syncthreads();
#pragma unroll
    for (int m = 0; m < 8; ++m) {
      int d = ((2 * m) & 3) + 8 * (m >> 1) + 4 * hi;  // even -> 8B-aligned pair
      f32x2 v;
      v[0] = (dt ? ot1[2 * m]     : ot0[2 * m])     * scl;
      v[1] = (dt ? ot1[2 * m + 1] : ot0[2 * m + 1]) * scl;
      *(f32x2*)&ep[ql * 36 + d] = v;
    }
    __syncthreads();
#pragma unroll
    for (int p = 0; p < 4; ++p) {
      int q = p * 8 + (lane >> 3);
      int cc = (lane & 7) * 4;
      f32x4 v = *(const f32x4*)&ep[q * 36 + cc];
      *(f32x4*)&outp[(size_t)q * kD + dt * 32 + cc] = v;
    }
  }
  if (split && hi == 0) {
    float* wm = Wg + (size_t)sc * CHUNK_F + 8192;
    wm[wid * 32 + ql]       = m_s;   // m at [8192,8320)
    wm[128 + wid * 32 + ql] = l_s;   // l at [8320,8448)
  }
}

// Merge the two KV-half partials of each split q-block (j=8..15).
__global__ __launch_bounds__(256)
void fa_merge(const float* __restrict__ Wg, float* __restrict__ Og) {
  const int bid = (int)blockIdx.x;        // 256 = 32 batches x 8 q-blocks
  const int b = bid >> 3, e = bid & 7;
  const int j = 8 + e;
  const float* w0 = Wg + (size_t)(b * 16 + 2 * (15 - j)) * CHUNK_F;
  const float* w1 = w0 + CHUNK_F;
  const int tid = (int)threadIdx.x;
  const int r = tid >> 1, ch = (tid & 1) * 32;
  const float m0 = w0[8192 + r], m1 = w1[8192 + r];
  const float l0 = w0[8320 + r], l1 = w1[8320 + r];
  const float M = fmaxf(m0, m1);
  float a = __expf(m0 - M), c = __expf(m1 - M);
  const float inv = 1.0f / (a * l0 + c * l1);
  a *= inv; c *= inv;
  float* orow = Og + ((size_t)b * kT + (size_t)j * QB + r) * kD + ch;
  const float* p0 = w0 + (size_t)r * kD + ch;
  const float* p1 = w1 + (size_t)r * kD + ch;
#pragma unroll
  for (int k = 0; k < 8; ++k) {
    f32x4 x0 = ((const f32x4*)p0)[k], x1 = ((const f32x4*)p1)[k];
    f32x4 o;
#pragma unroll
    for (int q = 0; q < 4; ++q) o[q] = a * x0[q] + c * x1[q];
    ((f32x4*)orow)[k] = o;
  }
}

extern "C" void kernel_launch(void* const* d_in, const int* in_sizes, int n_in,
                              void* d_out, int out_size, void* d_ws, size_t ws_size,
                              hipStream_t stream) {
  const float* Q = (const float*)d_in[0];
  const float* K = (const float*)d_in[1];
  const float* V = (const float*)d_in[2];
  float* O = (float*)d_out;
  const int mode = (ws_size >= WS_NEED) ? 1 : 0;  // constant across calls
  dim3 grid(mode ? 24 * kB : 16 * kB);
  fa_part<<<grid, 256, 0, stream>>>(Q, K, V, O, (float*)d_ws, mode);
  if (mode) fa_merge<<<dim3(256), 256, 0, stream>>>((const float*)d_ws, O);
}